// Round 5
// baseline (700.596 us; speedup 1.0000x reference)
//
#include <hip/hip_runtime.h>
#include <math.h>

__device__ __forceinline__ float sigf(float x) { return 1.0f / (1.0f + expf(-x)); }

// sorted insert into named scalars (bd0..bd3 / bj0..bj3), ascending by (d, idx)
// — matches jax.lax.top_k stable lower-index-first tie-break (total order).
#define INS4(D, J) do {                                                              \
    float _d = (D); int _j = (J);                                                    \
    if (_d < bd3 || (_d == bd3 && _j < bj3)) {                                       \
        bd3 = _d; bj3 = _j;                                                          \
        if (bd3 < bd2 || (bd3 == bd2 && bj3 < bj2)) {                                \
            float _t = bd2; bd2 = bd3; bd3 = _t; int _u = bj2; bj2 = bj3; bj3 = _u; }\
        if (bd2 < bd1 || (bd2 == bd1 && bj2 < bj1)) {                                \
            float _t = bd1; bd1 = bd2; bd2 = _t; int _u = bj1; bj1 = bj2; bj2 = _u; }\
        if (bd1 < bd0 || (bd1 == bd0 && bj1 < bj0)) {                                \
            float _t = bd0; bd0 = bd1; bd1 = _t; int _u = bj0; bj0 = bj1; bj1 = _u; }\
    } } while (0)

// Diagnostic: on host-side size mismatch, encode the failed check into out[0].
__global__ void diag_kernel(float* out, int code, int out_size) {
    if (out_size > 0) out[0] = (float)code * 1.0e8f;
}

// Fused kernel. Block = 256 threads = 16 pedestrians (16 lanes each).
__global__ __launch_bounds__(256) void nnlstm_fused(
    const float* __restrict__ obs1, const float* __restrict__ obs2,
    const float* __restrict__ h,    const float* __restrict__ c,
    const float* __restrict__ Wemb, const float* __restrict__ bemb,
    const float* __restrict__ Wih,  const float* __restrict__ bih,
    const float* __restrict__ Whh,  const float* __restrict__ bhh,
    const float* __restrict__ Wp,   const float* __restrict__ bp,
    int n, float* __restrict__ out)
{
    __shared__ float sMd[16][64];   //  4 KB  per-lane top-4 dists
    __shared__ int   sMj[16][64];   //  4 KB  per-lane top-4 indices
    __shared__ float sX[16][292];   // 18.7 KB  [row][k]: k<32 emb, 32..287 h
    __shared__ float sH[16][264];   // 16.9 KB  h_new

    const int t   = threadIdx.x;
    const int sub = t & 15;          // lane within pedestrian group
    const int ii  = t >> 4;          // pedestrian within block (0..15)
    const int i0  = blockIdx.x * 16;
    const int i   = i0 + ii;

    // cooperative load of h rows into sX[:, 32:288]
    for (int v = t; v < 16 * 256; v += 256) {
        int r = v >> 8, k = v & 255;
        int row = i0 + r;
        sX[r][32 + k] = (row < n) ? h[(size_t)row * 256 + k] : 0.0f;
    }

    // ---- Phase A: per-lane strided top-4 scan (compare on dist = sqrt(d2), as np does) ----
    float bd0 = 1e30f, bd1 = 1e30f, bd2 = 1e30f, bd3 = 1e30f;
    int   bj0 = 0x7fffffff, bj1 = 0x7fffffff, bj2 = 0x7fffffff, bj3 = 0x7fffffff;

    if (i < n) {
        const float pix = obs2[2 * i];
        const float piy = obs2[2 * i + 1];
        for (int j = sub; j < n; j += 16) {
            float dx = obs2[2 * j]     - pix;
            float dy = obs2[2 * j + 1] - piy;
            // match np rounding: no FMA contraction, then correctly-rounded sqrt
            float d2 = __fadd_rn(__fmul_rn(dx, dx), __fmul_rn(dy, dy));
            float dist = __fsqrt_rn(d2);
            if (j == i) continue;
            INS4(dist, j);
        }
    }
    sMd[ii][sub * 4 + 0] = bd0;  sMj[ii][sub * 4 + 0] = bj0;
    sMd[ii][sub * 4 + 1] = bd1;  sMj[ii][sub * 4 + 1] = bj1;
    sMd[ii][sub * 4 + 2] = bd2;  sMj[ii][sub * 4 + 2] = bj2;
    sMd[ii][sub * 4 + 3] = bd3;  sMj[ii][sub * 4 + 3] = bj3;
    __syncthreads();

    // ---- serial merge (thread r handles pedestrian r) + Linear(4,8)+ReLU embedding ----
    if (t < 16) {
        const int r = t;
        const int irow = i0 + r;
        float bd0 = 1e30f, bd1 = 1e30f, bd2 = 1e30f, bd3 = 1e30f;
        int   bj0 = 0x7fffffff, bj1 = 0x7fffffff, bj2 = 0x7fffffff, bj3 = 0x7fffffff;
        for (int q = 0; q < 64; q++) { INS4(sMd[r][q], sMj[r][q]); }

        if (irow < n) {
            float pix = obs2[2 * irow], piy = obs2[2 * irow + 1];
            float vix = pix - obs1[2 * irow];
            float viy = piy - obs1[2 * irow + 1];
            #pragma unroll
            for (int q2 = 0; q2 < 4; q2++) {
                int jn = (q2 == 0) ? bj0 : (q2 == 1) ? bj1 : (q2 == 2) ? bj2 : bj3;
                if (jn < 0 || jn >= n) jn = 0;   // safety clamp
                float pjx = obs2[2 * jn], pjy = obs2[2 * jn + 1];
                float px = pjx - pix, py = pjy - piy;
                float vx = (pjx - obs1[2 * jn])     - vix;
                float vy = (pjy - obs1[2 * jn + 1]) - viy;
                #pragma unroll
                for (int e = 0; e < 8; e++) {
                    float a = px * Wemb[e]      + py * Wemb[8 + e]
                            + vx * Wemb[16 + e] + vy * Wemb[24 + e]
                            + bemb[e];
                    sX[r][q2 * 8 + e] = fmaxf(a, 0.0f);
                }
            }
        } else {
            for (int e = 0; e < 32; e++) sX[r][e] = 0.0f;
        }
    }
    __syncthreads();

    // ---- Phase B: gates GEMM — thread t = hidden unit uu, 4 gates, 16 rows ----
    const int uu = t;
    float acc[4][16];
    #pragma unroll
    for (int j = 0; j < 4; j++) {
        float b = bih[uu + 256 * j] + bhh[uu + 256 * j];
        #pragma unroll
        for (int r = 0; r < 16; r++) acc[j][r] = b;
    }

    for (int kc = 0; kc < 288; kc++) {
        float w[4];
        #pragma unroll
        for (int j = 0; j < 4; j++) {
            int g = uu + 256 * j;
            w[j] = (kc < 32) ? Wih[(size_t)g * 32 + kc]
                             : Whh[(size_t)g * 256 + (kc - 32)];
        }
        #pragma unroll
        for (int r = 0; r < 16; r++) {
            float x = sX[r][kc];   // wave-broadcast LDS read
            #pragma unroll
            for (int j = 0; j < 4; j++) acc[j][r] += w[j] * x;
        }
    }

    // LSTM pointwise — gate order (i, f, g, o)
    for (int r = 0; r < 16; r++) {
        int row = i0 + r;
        float cin = (row < n) ? c[(size_t)row * 256 + uu] : 0.0f;
        float cn = sigf(acc[1][r]) * cin + sigf(acc[0][r]) * tanhf(acc[2][r]);
        float hn = sigf(acc[3][r]) * tanhf(cn);
        sH[r][uu] = hn;
    }
    __syncthreads();

    // out = h_new @ W_pool^T + b_pool
    for (int v = t; v < 16 * 32; v += 256) {
        int r = v >> 5, o = v & 31;
        int row = i0 + r;
        if (row >= n) continue;
        float a = bp[o];
        for (int kc = 0; kc < 256; kc++)
            a += Wp[(size_t)o * 256 + kc] * sH[r][kc];
        out[(size_t)row * 32 + o] = a;
    }
}

extern "C" void kernel_launch(void* const* d_in, const int* in_sizes, int n_in,
                              void* d_out, int out_size, void* d_ws, size_t ws_size,
                              hipStream_t stream) {
    float* out = (float*)d_out;

    // ---- host-side shape validation; encode failures into out[0] via diag ----
    int code = 0, n = 0;
    if (n_in != 12) code = 1;
    else {
        n = in_sizes[1] / 2;
        if (n <= 4 || in_sizes[1] != 2 * n)          code = 2;   // obs2 [n,2]
        else if (in_sizes[0]  != 2 * n)              code = 3;   // obs1 [n,2]
        else if (in_sizes[2]  != 256 * n)            code = 4;   // h [n,256]
        else if (in_sizes[3]  != 256 * n)            code = 5;   // c [n,256]
        else if (in_sizes[4]  != 32 || in_sizes[5] != 8)        code = 6;   // W_emb, b_emb
        else if (in_sizes[6]  != 32768 || in_sizes[7] != 1024)  code = 7;   // W_ih, b_ih
        else if (in_sizes[8]  != 262144 || in_sizes[9] != 1024) code = 8;   // W_hh, b_hh
        else if (in_sizes[10] != 8192 || in_sizes[11] != 32)    code = 9;   // W_pool, b_pool
        else if (out_size != 32 * n)                 code = 10;
    }
    if (code != 0) {
        diag_kernel<<<1, 1, 0, stream>>>(out, code, out_size);
        return;
    }

    const float* obs1   = (const float*)d_in[0];
    const float* obs2   = (const float*)d_in[1];
    const float* h      = (const float*)d_in[2];
    const float* c      = (const float*)d_in[3];
    const float* W_emb  = (const float*)d_in[4];
    const float* b_emb  = (const float*)d_in[5];
    const float* W_ih   = (const float*)d_in[6];
    const float* b_ih   = (const float*)d_in[7];
    const float* W_hh   = (const float*)d_in[8];
    const float* b_hh   = (const float*)d_in[9];
    const float* W_pool = (const float*)d_in[10];
    const float* b_pool = (const float*)d_in[11];

    int grid = (n + 15) / 16;
    nnlstm_fused<<<grid, 256, 0, stream>>>(
        obs1, obs2, h, c, W_emb, b_emb, W_ih, b_ih, W_hh, b_hh,
        W_pool, b_pool, n, out);
}

// Round 6
// 262.828 us; speedup vs baseline: 2.6656x; 2.6656x over previous
//
#include <hip/hip_runtime.h>
#include <math.h>

__device__ __forceinline__ float sigf(float x) { return 1.0f / (1.0f + expf(-x)); }

// sorted insert into named scalars (bd0..bd3 / bj0..bj3), ascending by (d, idx)
// — matches jax.lax.top_k stable lower-index-first tie-break (total order).
#define INS4(D, J) do {                                                              \
    float _d = (D); int _j = (J);                                                    \
    if (_d < bd3 || (_d == bd3 && _j < bj3)) {                                       \
        bd3 = _d; bj3 = _j;                                                          \
        if (bd3 < bd2 || (bd3 == bd2 && bj3 < bj2)) {                                \
            float _t = bd2; bd2 = bd3; bd3 = _t; int _u = bj2; bj2 = bj3; bj3 = _u; }\
        if (bd2 < bd1 || (bd2 == bd1 && bj2 < bj1)) {                                \
            float _t = bd1; bd1 = bd2; bd2 = _t; int _u = bj1; bj1 = bj2; bj2 = _u; }\
        if (bd1 < bd0 || (bd1 == bd0 && bj1 < bj0)) {                                \
            float _t = bd0; bd0 = bd1; bd1 = _t; int _u = bj0; bj0 = bj1; bj1 = _u; }\
    } } while (0)

__global__ void diag_kernel(float* out, int code, int out_size) {
    if (out_size > 0) out[0] = (float)code * 1.0e8f;
}

// Kernel 0: W^T into d_ws — WT[k][g] = (k<32 ? Wih[g*32+k] : Whh[g*256+k-32]).
// Writes coalesced; uncoalesced reads are a one-pass 1.13 MB cost (negligible).
__global__ __launch_bounds__(256) void transpose_w(
    const float* __restrict__ Wih, const float* __restrict__ Whh,
    float* __restrict__ WT)
{
    int id = blockIdx.x * 256 + threadIdx.x;     // over 288*1024
    if (id >= 288 * 1024) return;
    int k = id >> 10, g = id & 1023;
    WT[id] = (k < 32) ? Wih[(size_t)g * 32 + k] : Whh[(size_t)g * 256 + (k - 32)];
}

// Main fused kernel. Block = 256 threads = 16 pedestrians.
// LDS: sX 18.7 KB + 57.3 KB union(pos+merge | sWp) = 76 KB -> 2 blocks/CU.
__global__ __launch_bounds__(256) void nnlstm_fused(
    const float* __restrict__ obs1, const float* __restrict__ obs2,
    const float* __restrict__ h,    const float* __restrict__ c,
    const float* __restrict__ Wemb, const float* __restrict__ bemb,
    const float* __restrict__ WT,   const float* __restrict__ bih,
    const float* __restrict__ bhh,
    const float* __restrict__ Wp,   const float* __restrict__ bp,
    int n, float* __restrict__ out)
{
    __shared__ float sX[16][292];                 // [row][k]: k<32 emb, 32..287 h (18,688 B)
    __shared__ __align__(16) char uni[57344];     // union region
    float2* pos = (float2*)uni;                   // Phase A: obs2 staged (49,152 B)
    float*  sMd = (float*)(uni + 49152);          // Phase A: per-lane top-4 dists (4,096 B)
    int*    sMj = (int*)(uni + 53248);            // Phase A: per-lane top-4 idx   (4,096 B)
    float*  sWp = (float*)uni;                    // Phase C: W_pool [32][257] (32,896 B; aliases pos)
    float*  sH  = &sX[0][0];                      // Phase C: h_new [16][264] overlays dead sX

    const int t   = threadIdx.x;
    const int sub = t & 15;
    const int ii  = t >> 4;
    const int i0  = blockIdx.x * 16;
    const int i   = i0 + ii;

    // ---- stage obs2 -> pos (coalesced float2) and h -> sX[:,32:288] (float4) ----
    for (int v = t; v < n; v += 256) {
        pos[v] = ((const float2*)obs2)[v];
    }
    for (int f = t; f < 16 * 64; f += 256) {      // 1024 float4 = 16 rows x 256
        int r = f >> 6, k = (f & 63) * 4;
        int row = i0 + r;
        float4 hv = (row < n) ? ((const float4*)h)[(size_t)row * 64 + (k >> 2)]
                              : make_float4(0.f, 0.f, 0.f, 0.f);
        *(float4*)&sX[r][32 + k] = hv;
    }
    __syncthreads();   // B1

    // ---- Phase A: per-lane strided top-4 scan from LDS ----
    float bd0 = 1e30f, bd1 = 1e30f, bd2 = 1e30f, bd3 = 1e30f;
    int   bj0 = 0x7fffffff, bj1 = 0x7fffffff, bj2 = 0x7fffffff, bj3 = 0x7fffffff;

    if (i < n) {
        const float2 pi = pos[i];
        for (int j = sub; j < n; j += 16) {
            float2 pj = pos[j];
            float dx = pj.x - pi.x, dy = pj.y - pi.y;
            // match np rounding: no FMA contraction, correctly-rounded sqrt
            float d2 = __fadd_rn(__fmul_rn(dx, dx), __fmul_rn(dy, dy));
            float dist = __fsqrt_rn(d2);
            if (j == i) continue;
            INS4(dist, j);
        }
    }
    sMd[ii * 64 + sub * 4 + 0] = bd0;  sMj[ii * 64 + sub * 4 + 0] = bj0;
    sMd[ii * 64 + sub * 4 + 1] = bd1;  sMj[ii * 64 + sub * 4 + 1] = bj1;
    sMd[ii * 64 + sub * 4 + 2] = bd2;  sMj[ii * 64 + sub * 4 + 2] = bj2;
    sMd[ii * 64 + sub * 4 + 3] = bd3;  sMj[ii * 64 + sub * 4 + 3] = bj3;
    __syncthreads();   // B2  (pos dead after this point)

    // ---- merge + embedding (t<16), W_pool -> sWp coop-load (t>=64) ----
    if (t < 16) {
        const int r = t;
        const int irow = i0 + r;
        float bd0 = 1e30f, bd1 = 1e30f, bd2 = 1e30f, bd3 = 1e30f;
        int   bj0 = 0x7fffffff, bj1 = 0x7fffffff, bj2 = 0x7fffffff, bj3 = 0x7fffffff;
        for (int q = 0; q < 64; q++) { INS4(sMd[r * 64 + q], sMj[r * 64 + q]); }

        if (irow < n) {
            float pix = obs2[2 * irow], piy = obs2[2 * irow + 1];
            float vix = pix - obs1[2 * irow];
            float viy = piy - obs1[2 * irow + 1];
            #pragma unroll
            for (int q2 = 0; q2 < 4; q2++) {
                int jn = (q2 == 0) ? bj0 : (q2 == 1) ? bj1 : (q2 == 2) ? bj2 : bj3;
                if (jn < 0 || jn >= n) jn = 0;   // safety clamp
                float pjx = obs2[2 * jn], pjy = obs2[2 * jn + 1];
                float px = pjx - pix, py = pjy - piy;
                float vx = (pjx - obs1[2 * jn])     - vix;
                float vy = (pjy - obs1[2 * jn + 1]) - viy;
                #pragma unroll
                for (int e = 0; e < 8; e++) {
                    float a = px * Wemb[e]      + py * Wemb[8 + e]
                            + vx * Wemb[16 + e] + vy * Wemb[24 + e]
                            + bemb[e];
                    sX[r][q2 * 8 + e] = fmaxf(a, 0.0f);
                }
            }
        } else {
            for (int e = 0; e < 32; e++) sX[r][e] = 0.0f;
        }
    } else if (t >= 64) {
        // stage W_pool [32][256] into sWp with pad-257 rows (conflict-free later)
        for (int f = t - 64; f < 2048; f += 192) {      // 2048 float4
            float4 w4 = ((const float4*)Wp)[f];
            int base = f * 4;
            int o = base >> 8, k0 = base & 255;
            float* dst = &sWp[o * 257 + k0];
            dst[0] = w4.x; dst[1] = w4.y; dst[2] = w4.z; dst[3] = w4.w;
        }
    }
    __syncthreads();   // B3

    // ---- Phase B: gates GEMM. thread t = unit uu, gates {uu,uu+256,uu+512,uu+768}, 16 rows.
    // W^T reads are fully coalesced; X reads are wave-uniform b128 broadcasts.
    const int uu = t;
    float acc[4][16];
    #pragma unroll
    for (int j = 0; j < 4; j++) {
        float b = bih[uu + 256 * j] + bhh[uu + 256 * j];
        #pragma unroll
        for (int r = 0; r < 16; r++) acc[j][r] = b;
    }

    for (int kc = 0; kc < 288; kc += 4) {
        const float* wb = WT + (size_t)kc * 1024 + uu;
        float w0[4], w1[4], w2[4], w3[4];
        #pragma unroll
        for (int j = 0; j < 4; j++) {
            w0[j] = wb[0 * 1024 + j * 256];
            w1[j] = wb[1 * 1024 + j * 256];
            w2[j] = wb[2 * 1024 + j * 256];
            w3[j] = wb[3 * 1024 + j * 256];
        }
        #pragma unroll
        for (int r = 0; r < 16; r++) {
            float4 x = *(const float4*)&sX[r][kc];
            #pragma unroll
            for (int j = 0; j < 4; j++) {
                acc[j][r] += w0[j] * x.x + w1[j] * x.y + w2[j] * x.z + w3[j] * x.w;
            }
        }
    }
    __syncthreads();   // B4  (all sX reads done before sH overwrite)

    // ---- LSTM pointwise (gate order i,f,g,o); h_new -> sH (overlaying sX) ----
    for (int r = 0; r < 16; r++) {
        int row = i0 + r;
        float cin = (row < n) ? c[(size_t)row * 256 + uu] : 0.0f;
        float cn = sigf(acc[1][r]) * cin + sigf(acc[0][r]) * tanhf(acc[2][r]);
        float hn = sigf(acc[3][r]) * tanhf(cn);
        sH[r * 264 + uu] = hn;
    }
    __syncthreads();   // B5

    // ---- Phase C: out = h_new @ W_pool^T + b_pool (from LDS) ----
    for (int v = t; v < 512; v += 256) {
        int r = v >> 5, o = v & 31;
        int row = i0 + r;
        if (row >= n) continue;
        float a = bp[o];
        const float* wrow = &sWp[o * 257];
        const float* hrow = &sH[r * 264];
        for (int kc = 0; kc < 256; kc++)
            a += wrow[kc] * hrow[kc];
        out[(size_t)row * 32 + o] = a;
    }
}

// ---- proven round-5 fallback (used only if ws_size is too small for W^T) ----
__global__ __launch_bounds__(256) void nnlstm_fallback(
    const float* __restrict__ obs1, const float* __restrict__ obs2,
    const float* __restrict__ h,    const float* __restrict__ c,
    const float* __restrict__ Wemb, const float* __restrict__ bemb,
    const float* __restrict__ Wih,  const float* __restrict__ bih,
    const float* __restrict__ Whh,  const float* __restrict__ bhh,
    const float* __restrict__ Wp,   const float* __restrict__ bp,
    int n, float* __restrict__ out)
{
    __shared__ float sMd[16][64];
    __shared__ int   sMj[16][64];
    __shared__ float sX[16][292];
    __shared__ float sH[16][264];

    const int t   = threadIdx.x;
    const int sub = t & 15;
    const int ii  = t >> 4;
    const int i0  = blockIdx.x * 16;
    const int i   = i0 + ii;

    for (int v = t; v < 16 * 256; v += 256) {
        int r = v >> 8, k = v & 255;
        int row = i0 + r;
        sX[r][32 + k] = (row < n) ? h[(size_t)row * 256 + k] : 0.0f;
    }

    float bd0 = 1e30f, bd1 = 1e30f, bd2 = 1e30f, bd3 = 1e30f;
    int   bj0 = 0x7fffffff, bj1 = 0x7fffffff, bj2 = 0x7fffffff, bj3 = 0x7fffffff;

    if (i < n) {
        const float pix = obs2[2 * i];
        const float piy = obs2[2 * i + 1];
        for (int j = sub; j < n; j += 16) {
            float dx = obs2[2 * j]     - pix;
            float dy = obs2[2 * j + 1] - piy;
            float d2 = __fadd_rn(__fmul_rn(dx, dx), __fmul_rn(dy, dy));
            float dist = __fsqrt_rn(d2);
            if (j == i) continue;
            INS4(dist, j);
        }
    }
    sMd[ii][sub * 4 + 0] = bd0;  sMj[ii][sub * 4 + 0] = bj0;
    sMd[ii][sub * 4 + 1] = bd1;  sMj[ii][sub * 4 + 1] = bj1;
    sMd[ii][sub * 4 + 2] = bd2;  sMj[ii][sub * 4 + 2] = bj2;
    sMd[ii][sub * 4 + 3] = bd3;  sMj[ii][sub * 4 + 3] = bj3;
    __syncthreads();

    if (t < 16) {
        const int r = t;
        const int irow = i0 + r;
        float bd0 = 1e30f, bd1 = 1e30f, bd2 = 1e30f, bd3 = 1e30f;
        int   bj0 = 0x7fffffff, bj1 = 0x7fffffff, bj2 = 0x7fffffff, bj3 = 0x7fffffff;
        for (int q = 0; q < 64; q++) { INS4(sMd[r][q], sMj[r][q]); }

        if (irow < n) {
            float pix = obs2[2 * irow], piy = obs2[2 * irow + 1];
            float vix = pix - obs1[2 * irow];
            float viy = piy - obs1[2 * irow + 1];
            #pragma unroll
            for (int q2 = 0; q2 < 4; q2++) {
                int jn = (q2 == 0) ? bj0 : (q2 == 1) ? bj1 : (q2 == 2) ? bj2 : bj3;
                if (jn < 0 || jn >= n) jn = 0;
                float pjx = obs2[2 * jn], pjy = obs2[2 * jn + 1];
                float px = pjx - pix, py = pjy - piy;
                float vx = (pjx - obs1[2 * jn])     - vix;
                float vy = (pjy - obs1[2 * jn + 1]) - viy;
                #pragma unroll
                for (int e = 0; e < 8; e++) {
                    float a = px * Wemb[e]      + py * Wemb[8 + e]
                            + vx * Wemb[16 + e] + vy * Wemb[24 + e]
                            + bemb[e];
                    sX[r][q2 * 8 + e] = fmaxf(a, 0.0f);
                }
            }
        } else {
            for (int e = 0; e < 32; e++) sX[r][e] = 0.0f;
        }
    }
    __syncthreads();

    const int uu = t;
    float acc[4][16];
    #pragma unroll
    for (int j = 0; j < 4; j++) {
        float b = bih[uu + 256 * j] + bhh[uu + 256 * j];
        #pragma unroll
        for (int r = 0; r < 16; r++) acc[j][r] = b;
    }

    for (int kc = 0; kc < 288; kc++) {
        float w[4];
        #pragma unroll
        for (int j = 0; j < 4; j++) {
            int g = uu + 256 * j;
            w[j] = (kc < 32) ? Wih[(size_t)g * 32 + kc]
                             : Whh[(size_t)g * 256 + (kc - 32)];
        }
        #pragma unroll
        for (int r = 0; r < 16; r++) {
            float x = sX[r][kc];
            #pragma unroll
            for (int j = 0; j < 4; j++) acc[j][r] += w[j] * x;
        }
    }

    for (int r = 0; r < 16; r++) {
        int row = i0 + r;
        float cin = (row < n) ? c[(size_t)row * 256 + uu] : 0.0f;
        float cn = sigf(acc[1][r]) * cin + sigf(acc[0][r]) * tanhf(acc[2][r]);
        float hn = sigf(acc[3][r]) * tanhf(cn);
        sH[r][uu] = hn;
    }
    __syncthreads();

    for (int v = t; v < 16 * 32; v += 256) {
        int r = v >> 5, o = v & 31;
        int row = i0 + r;
        if (row >= n) continue;
        float a = bp[o];
        for (int kc = 0; kc < 256; kc++)
            a += Wp[(size_t)o * 256 + kc] * sH[r][kc];
        out[(size_t)row * 32 + o] = a;
    }
}

extern "C" void kernel_launch(void* const* d_in, const int* in_sizes, int n_in,
                              void* d_out, int out_size, void* d_ws, size_t ws_size,
                              hipStream_t stream) {
    float* out = (float*)d_out;

    int code = 0, n = 0;
    if (n_in != 12) code = 1;
    else {
        n = in_sizes[1] / 2;
        if (n <= 4 || in_sizes[1] != 2 * n)          code = 2;
        else if (in_sizes[0]  != 2 * n)              code = 3;
        else if (in_sizes[2]  != 256 * n)            code = 4;
        else if (in_sizes[3]  != 256 * n)            code = 5;
        else if (in_sizes[4]  != 32 || in_sizes[5] != 8)        code = 6;
        else if (in_sizes[6]  != 32768 || in_sizes[7] != 1024)  code = 7;
        else if (in_sizes[8]  != 262144 || in_sizes[9] != 1024) code = 8;
        else if (in_sizes[10] != 8192 || in_sizes[11] != 32)    code = 9;
        else if (out_size != 32 * n)                 code = 10;
    }
    if (code != 0) {
        diag_kernel<<<1, 1, 0, stream>>>(out, code, out_size);
        return;
    }

    const float* obs1   = (const float*)d_in[0];
    const float* obs2   = (const float*)d_in[1];
    const float* h      = (const float*)d_in[2];
    const float* c      = (const float*)d_in[3];
    const float* W_emb  = (const float*)d_in[4];
    const float* b_emb  = (const float*)d_in[5];
    const float* W_ih   = (const float*)d_in[6];
    const float* b_ih   = (const float*)d_in[7];
    const float* W_hh   = (const float*)d_in[8];
    const float* b_hh   = (const float*)d_in[9];
    const float* W_pool = (const float*)d_in[10];
    const float* b_pool = (const float*)d_in[11];

    int grid = (n + 15) / 16;
    const size_t wt_bytes = (size_t)288 * 1024 * sizeof(float);

    if (ws_size >= wt_bytes) {
        float* WT = (float*)d_ws;
        transpose_w<<<(288 * 1024 + 255) / 256, 256, 0, stream>>>(W_ih, W_hh, WT);
        nnlstm_fused<<<grid, 256, 0, stream>>>(
            obs1, obs2, h, c, W_emb, b_emb, WT, b_ih, b_hh,
            W_pool, b_pool, n, out);
    } else {
        nnlstm_fallback<<<grid, 256, 0, stream>>>(
            obs1, obs2, h, c, W_emb, b_emb, W_ih, b_ih, W_hh, b_hh,
            W_pool, b_pool, n, out);
    }
}

// Round 7
// 204.155 us; speedup vs baseline: 3.4317x; 1.2874x over previous
//
#include <hip/hip_runtime.h>
#include <math.h>

typedef unsigned short u16;
typedef __attribute__((ext_vector_type(8))) short bf16x8;
typedef __attribute__((ext_vector_type(4))) float f32x4;

__device__ __forceinline__ float sigf(float x) { return 1.0f / (1.0f + expf(-x)); }
__device__ __forceinline__ u16 f2bf(float f) {
    unsigned x = __float_as_uint(f);
    return (u16)((x + 0x7fffu + ((x >> 16) & 1u)) >> 16);
}

// sorted insert, ascending by (d, idx) — matches jax.lax.top_k stable tie-break.
#define INS4(D, J) do {                                                              \
    float _d = (D); int _j = (J);                                                    \
    if (_d < bd3 || (_d == bd3 && _j < bj3)) {                                       \
        bd3 = _d; bj3 = _j;                                                          \
        if (bd3 < bd2 || (bd3 == bd2 && bj3 < bj2)) {                                \
            float _t = bd2; bd2 = bd3; bd3 = _t; int _u = bj2; bj2 = bj3; bj3 = _u; }\
        if (bd2 < bd1 || (bd2 == bd1 && bj2 < bj1)) {                                \
            float _t = bd1; bd1 = bd2; bd2 = _t; int _u = bj1; bj1 = bj2; bj2 = _u; }\
        if (bd1 < bd0 || (bd1 == bd0 && bj1 < bj0)) {                                \
            float _t = bd0; bd0 = bd1; bd1 = _t; int _u = bj0; bj0 = bj1; bj1 = _u; }\
    } } while (0)

__global__ void diag_kernel(float* out, int code, int out_size) {
    if (out_size > 0) out[0] = (float)code * 1.0e8f;
}

// Prep: bf16 weight copies. Wg[g][0..287] = [Wih row g (32) | Whh row g (256)],
// Wpb[o][0..255] = Wp row o. Reads and writes both coalesced (k-contiguous).
__global__ __launch_bounds__(256) void prep_bf16(
    const float* __restrict__ Wih, const float* __restrict__ Whh,
    const float* __restrict__ Wp,
    u16* __restrict__ Wg, u16* __restrict__ Wpb)
{
    int id = blockIdx.x * 256 + threadIdx.x;
    if (id < 1024 * 288) {
        int g = id / 288, k = id - g * 288;
        float v = (k < 32) ? Wih[(size_t)g * 32 + k] : Whh[(size_t)g * 256 + (k - 32)];
        Wg[id] = f2bf(v);
    } else {
        int id2 = id - 1024 * 288;
        if (id2 < 32 * 256) Wpb[id2] = f2bf(Wp[id2]);
    }
}

// Main fused kernel. Block = 256 threads = 16 pedestrians.
// LDS 75,072 B -> 2 blocks/CU.
//   [0,     9472): sXb  u16[16][296]  X=[emb|h] bf16  (later reused as sHb u16[16][264])
//   [9472, 75072): union:
//       Phase A: pos f2[6144] (49,152) | sMd f32[1024] | sMj i32[1024]
//       Phase B: gbuf f32[16][1025] (65,600)
__global__ __launch_bounds__(256) void nnlstm_mfma(
    const float* __restrict__ obs1, const float* __restrict__ obs2,
    const float* __restrict__ h,    const float* __restrict__ c,
    const float* __restrict__ Wemb, const float* __restrict__ bemb,
    const u16*  __restrict__ Wg,    const float* __restrict__ bih,
    const float* __restrict__ bhh,
    const u16*  __restrict__ Wpb,   const float* __restrict__ bp,
    int n, float* __restrict__ out)
{
    __shared__ __align__(16) char lds[75072];
    u16*    sXb = (u16*)lds;                      // [16][296] bf16
    char*   uni = lds + 9472;
    float2* pos = (float2*)uni;                   // [6144]
    float*  sMd = (float*)(uni + 49152);          // [16][64]
    int*    sMj = (int*)(uni + 53248);            // [16][64]
    float*  gbuf = (float*)uni;                   // [16][1025] f32 gates
    u16*    sHb = (u16*)lds;                      // [16][264] bf16 h_new (overlays sXb)

    const int t    = threadIdx.x;
    const int sub  = t & 15;
    const int ii   = t >> 4;
    const int i0   = blockIdx.x * 16;
    const int i    = i0 + ii;
    const int lane = t & 63;
    const int wv   = t >> 6;          // wave id 0..3
    const int fm   = lane & 15;       // MFMA fragment m/n index
    const int fq   = lane >> 4;       // MFMA k-quad (0..3)

    // ---- stage obs2 -> pos (coalesced) and h -> sXb[:,32:288] as bf16 ----
    for (int v = t; v < n; v += 256) pos[v] = ((const float2*)obs2)[v];
    for (int f = t; f < 16 * 64; f += 256) {
        int r = f >> 6, k4 = f & 63;
        int row = i0 + r;
        float4 hv = (row < n) ? ((const float4*)h)[(size_t)row * 64 + k4]
                              : make_float4(0.f, 0.f, 0.f, 0.f);
        u16* d = &sXb[r * 296 + 32 + k4 * 4];
        d[0] = f2bf(hv.x); d[1] = f2bf(hv.y); d[2] = f2bf(hv.z); d[3] = f2bf(hv.w);
    }
    __syncthreads();   // B1

    // ---- Phase A: per-lane strided top-4 scan from LDS (semantics = round 5/6) ----
    float bd0 = 1e30f, bd1 = 1e30f, bd2 = 1e30f, bd3 = 1e30f;
    int   bj0 = 0x7fffffff, bj1 = 0x7fffffff, bj2 = 0x7fffffff, bj3 = 0x7fffffff;

    if (i < n) {
        const float2 pi = pos[i];
        for (int j = sub; j < n; j += 16) {
            float2 pj = pos[j];
            float dx = pj.x - pi.x, dy = pj.y - pi.y;
            float d2 = __fadd_rn(__fmul_rn(dx, dx), __fmul_rn(dy, dy));
            float dist = __fsqrt_rn(d2);
            if (j == i) continue;
            INS4(dist, j);
        }
    }
    sMd[ii * 64 + sub * 4 + 0] = bd0;  sMj[ii * 64 + sub * 4 + 0] = bj0;
    sMd[ii * 64 + sub * 4 + 1] = bd1;  sMj[ii * 64 + sub * 4 + 1] = bj1;
    sMd[ii * 64 + sub * 4 + 2] = bd2;  sMj[ii * 64 + sub * 4 + 2] = bj2;
    sMd[ii * 64 + sub * 4 + 3] = bd3;  sMj[ii * 64 + sub * 4 + 3] = bj3;
    __syncthreads();   // B2

    // ---- merge + Linear(4,8)+ReLU embedding -> sXb[:,0:32] bf16 (t<16) ----
    if (t < 16) {
        const int r = t;
        const int irow = i0 + r;
        float bd0 = 1e30f, bd1 = 1e30f, bd2 = 1e30f, bd3 = 1e30f;
        int   bj0 = 0x7fffffff, bj1 = 0x7fffffff, bj2 = 0x7fffffff, bj3 = 0x7fffffff;
        for (int q = 0; q < 64; q++) { INS4(sMd[r * 64 + q], sMj[r * 64 + q]); }

        if (irow < n) {
            float pix = obs2[2 * irow], piy = obs2[2 * irow + 1];
            float vix = pix - obs1[2 * irow];
            float viy = piy - obs1[2 * irow + 1];
            #pragma unroll
            for (int q2 = 0; q2 < 4; q2++) {
                int jn = (q2 == 0) ? bj0 : (q2 == 1) ? bj1 : (q2 == 2) ? bj2 : bj3;
                if (jn < 0 || jn >= n) jn = 0;   // safety clamp
                float pjx = obs2[2 * jn], pjy = obs2[2 * jn + 1];
                float px = pjx - pix, py = pjy - piy;
                float vx = (pjx - obs1[2 * jn])     - vix;
                float vy = (pjy - obs1[2 * jn + 1]) - viy;
                #pragma unroll
                for (int e = 0; e < 8; e++) {
                    float a = px * Wemb[e]      + py * Wemb[8 + e]
                            + vx * Wemb[16 + e] + vy * Wemb[24 + e]
                            + bemb[e];
                    sXb[r * 296 + q2 * 8 + e] = f2bf(fmaxf(a, 0.0f));
                }
            }
        } else {
            for (int e = 0; e < 32; e++) sXb[r * 296 + e] = 0;
        }
    }
    __syncthreads();   // B3 (pos/sMd/sMj dead; gbuf region free)

    // ---- Phase B: gates GEMM via MFMA. Wave wv covers gates [wv*256, wv*256+256). ----
    // A-frag: lane holds X[fm][kt*32 + fq*8 + j], j=0..7 (loaded once, 9 k-tiles).
    bf16x8 afr[9];
    #pragma unroll
    for (int kt = 0; kt < 9; kt++)
        afr[kt] = *(const bf16x8*)&sXb[fm * 296 + kt * 32 + fq * 8];

    for (int nt = 0; nt < 16; nt++) {
        const int g0 = wv * 256 + nt * 16;
        const u16* wrow = Wg + (size_t)(g0 + fm) * 288 + fq * 8;
        f32x4 acc = {0.f, 0.f, 0.f, 0.f};
        #pragma unroll
        for (int kt = 0; kt < 9; kt++) {
            bf16x8 bfr = *(const bf16x8*)(wrow + kt * 32);
            acc = __builtin_amdgcn_mfma_f32_16x16x32_bf16(afr[kt], bfr, acc, 0, 0, 0);
        }
        // D: col = fm (gate g0+fm), rows fq*4 + reg
        #pragma unroll
        for (int r_ = 0; r_ < 4; r_++)
            gbuf[(fq * 4 + r_) * 1025 + g0 + fm] = acc[r_];
    }
    __syncthreads();   // B4 (all sXb reads done; gbuf complete)

    // ---- LSTM pointwise (gate order i,f,g,o); thread t = hidden unit u ----
    {
        const int u = t;
        float b0 = bih[u]       + bhh[u];
        float b1 = bih[u + 256] + bhh[u + 256];
        float b2 = bih[u + 512] + bhh[u + 512];
        float b3 = bih[u + 768] + bhh[u + 768];
        for (int r = 0; r < 16; r++) {
            int row = i0 + r;
            float cin = (row < n) ? c[(size_t)row * 256 + u] : 0.0f;
            float gi = gbuf[r * 1025 + u]       + b0;
            float gf = gbuf[r * 1025 + u + 256] + b1;
            float gg = gbuf[r * 1025 + u + 512] + b2;
            float go = gbuf[r * 1025 + u + 768] + b3;
            float cn = sigf(gf) * cin + sigf(gi) * tanhf(gg);
            float hn = sigf(go) * tanhf(cn);
            sHb[r * 264 + u] = f2bf(hn);
        }
    }
    __syncthreads();   // B5

    // ---- Pool GEMM via MFMA: M=16 x N=32 x K=256; waves 0,1 take one n-tile each ----
    if (wv < 2) {
        bf16x8 ah[8];
        #pragma unroll
        for (int kt = 0; kt < 8; kt++)
            ah[kt] = *(const bf16x8*)&sHb[fm * 264 + kt * 32 + fq * 8];
        const u16* wrow = Wpb + (size_t)(wv * 16 + fm) * 256 + fq * 8;
        f32x4 acc = {0.f, 0.f, 0.f, 0.f};
        #pragma unroll
        for (int kt = 0; kt < 8; kt++) {
            bf16x8 bfr = *(const bf16x8*)(wrow + kt * 32);
            acc = __builtin_amdgcn_mfma_f32_16x16x32_bf16(ah[kt], bfr, acc, 0, 0, 0);
        }
        float bias = bp[wv * 16 + fm];
        #pragma unroll
        for (int r_ = 0; r_ < 4; r_++) {
            int row = i0 + fq * 4 + r_;
            if (row < n) out[(size_t)row * 32 + wv * 16 + fm] = acc[r_] + bias;
        }
    }
}

// ---- proven round-5 fallback (only if ws too small or n > 6144) ----
__global__ __launch_bounds__(256) void nnlstm_fallback(
    const float* __restrict__ obs1, const float* __restrict__ obs2,
    const float* __restrict__ h,    const float* __restrict__ c,
    const float* __restrict__ Wemb, const float* __restrict__ bemb,
    const float* __restrict__ Wih,  const float* __restrict__ bih,
    const float* __restrict__ Whh,  const float* __restrict__ bhh,
    const float* __restrict__ Wp,   const float* __restrict__ bp,
    int n, float* __restrict__ out)
{
    __shared__ float sMd[16][64];
    __shared__ int   sMj[16][64];
    __shared__ float sX[16][292];
    __shared__ float sH[16][264];

    const int t   = threadIdx.x;
    const int sub = t & 15;
    const int ii  = t >> 4;
    const int i0  = blockIdx.x * 16;
    const int i   = i0 + ii;

    for (int v = t; v < 16 * 256; v += 256) {
        int r = v >> 8, k = v & 255;
        int row = i0 + r;
        sX[r][32 + k] = (row < n) ? h[(size_t)row * 256 + k] : 0.0f;
    }

    float bd0 = 1e30f, bd1 = 1e30f, bd2 = 1e30f, bd3 = 1e30f;
    int   bj0 = 0x7fffffff, bj1 = 0x7fffffff, bj2 = 0x7fffffff, bj3 = 0x7fffffff;

    if (i < n) {
        const float pix = obs2[2 * i];
        const float piy = obs2[2 * i + 1];
        for (int j = sub; j < n; j += 16) {
            float dx = obs2[2 * j]     - pix;
            float dy = obs2[2 * j + 1] - piy;
            float d2 = __fadd_rn(__fmul_rn(dx, dx), __fmul_rn(dy, dy));
            float dist = __fsqrt_rn(d2);
            if (j == i) continue;
            INS4(dist, j);
        }
    }
    sMd[ii][sub * 4 + 0] = bd0;  sMj[ii][sub * 4 + 0] = bj0;
    sMd[ii][sub * 4 + 1] = bd1;  sMj[ii][sub * 4 + 1] = bj1;
    sMd[ii][sub * 4 + 2] = bd2;  sMj[ii][sub * 4 + 2] = bj2;
    sMd[ii][sub * 4 + 3] = bd3;  sMj[ii][sub * 4 + 3] = bj3;
    __syncthreads();

    if (t < 16) {
        const int r = t;
        const int irow = i0 + r;
        float bd0 = 1e30f, bd1 = 1e30f, bd2 = 1e30f, bd3 = 1e30f;
        int   bj0 = 0x7fffffff, bj1 = 0x7fffffff, bj2 = 0x7fffffff, bj3 = 0x7fffffff;
        for (int q = 0; q < 64; q++) { INS4(sMd[r][q], sMj[r][q]); }

        if (irow < n) {
            float pix = obs2[2 * irow], piy = obs2[2 * irow + 1];
            float vix = pix - obs1[2 * irow];
            float viy = piy - obs1[2 * irow + 1];
            #pragma unroll
            for (int q2 = 0; q2 < 4; q2++) {
                int jn = (q2 == 0) ? bj0 : (q2 == 1) ? bj1 : (q2 == 2) ? bj2 : bj3;
                if (jn < 0 || jn >= n) jn = 0;
                float pjx = obs2[2 * jn], pjy = obs2[2 * jn + 1];
                float px = pjx - pix, py = pjy - piy;
                float vx = (pjx - obs1[2 * jn])     - vix;
                float vy = (pjy - obs1[2 * jn + 1]) - viy;
                #pragma unroll
                for (int e = 0; e < 8; e++) {
                    float a = px * Wemb[e]      + py * Wemb[8 + e]
                            + vx * Wemb[16 + e] + vy * Wemb[24 + e]
                            + bemb[e];
                    sX[r][q2 * 8 + e] = fmaxf(a, 0.0f);
                }
            }
        } else {
            for (int e = 0; e < 32; e++) sX[r][e] = 0.0f;
        }
    }
    __syncthreads();

    const int uu = t;
    float acc[4][16];
    #pragma unroll
    for (int j = 0; j < 4; j++) {
        float b = bih[uu + 256 * j] + bhh[uu + 256 * j];
        #pragma unroll
        for (int r = 0; r < 16; r++) acc[j][r] = b;
    }

    for (int kc = 0; kc < 288; kc++) {
        float w[4];
        #pragma unroll
        for (int j = 0; j < 4; j++) {
            int g = uu + 256 * j;
            w[j] = (kc < 32) ? Wih[(size_t)g * 32 + kc]
                             : Whh[(size_t)g * 256 + (kc - 32)];
        }
        #pragma unroll
        for (int r = 0; r < 16; r++) {
            float x = sX[r][kc];
            #pragma unroll
            for (int j = 0; j < 4; j++) acc[j][r] += w[j] * x;
        }
    }

    for (int r = 0; r < 16; r++) {
        int row = i0 + r;
        float cin = (row < n) ? c[(size_t)row * 256 + uu] : 0.0f;
        float cn = sigf(acc[1][r]) * cin + sigf(acc[0][r]) * tanhf(acc[2][r]);
        float hn = sigf(acc[3][r]) * tanhf(cn);
        sH[r][uu] = hn;
    }
    __syncthreads();

    for (int v = t; v < 16 * 32; v += 256) {
        int r = v >> 5, o = v & 31;
        int row = i0 + r;
        if (row >= n) continue;
        float a = bp[o];
        for (int kc = 0; kc < 256; kc++)
            a += Wp[(size_t)o * 256 + kc] * sH[r][kc];
        out[(size_t)row * 32 + o] = a;
    }
}

extern "C" void kernel_launch(void* const* d_in, const int* in_sizes, int n_in,
                              void* d_out, int out_size, void* d_ws, size_t ws_size,
                              hipStream_t stream) {
    float* out = (float*)d_out;

    int code = 0, n = 0;
    if (n_in != 12) code = 1;
    else {
        n = in_sizes[1] / 2;
        if (n <= 4 || in_sizes[1] != 2 * n)          code = 2;
        else if (in_sizes[0]  != 2 * n)              code = 3;
        else if (in_sizes[2]  != 256 * n)            code = 4;
        else if (in_sizes[3]  != 256 * n)            code = 5;
        else if (in_sizes[4]  != 32 || in_sizes[5] != 8)        code = 6;
        else if (in_sizes[6]  != 32768 || in_sizes[7] != 1024)  code = 7;
        else if (in_sizes[8]  != 262144 || in_sizes[9] != 1024) code = 8;
        else if (in_sizes[10] != 8192 || in_sizes[11] != 32)    code = 9;
        else if (out_size != 32 * n)                 code = 10;
    }
    if (code != 0) {
        diag_kernel<<<1, 1, 0, stream>>>(out, code, out_size);
        return;
    }

    const float* obs1   = (const float*)d_in[0];
    const float* obs2   = (const float*)d_in[1];
    const float* h      = (const float*)d_in[2];
    const float* c      = (const float*)d_in[3];
    const float* W_emb  = (const float*)d_in[4];
    const float* b_emb  = (const float*)d_in[5];
    const float* W_ih   = (const float*)d_in[6];
    const float* b_ih   = (const float*)d_in[7];
    const float* W_hh   = (const float*)d_in[8];
    const float* b_hh   = (const float*)d_in[9];
    const float* W_pool = (const float*)d_in[10];
    const float* b_pool = (const float*)d_in[11];

    int grid = (n + 15) / 16;
    const size_t wg_bytes  = (size_t)1024 * 288 * sizeof(u16);   // 589,824
    const size_t wpb_bytes = (size_t)32 * 256 * sizeof(u16);     //  16,384

    if (ws_size >= wg_bytes + wpb_bytes && n <= 6144) {
        u16* Wg  = (u16*)d_ws;
        u16* Wpb = (u16*)((char*)d_ws + wg_bytes);
        int total = 1024 * 288 + 32 * 256;
        prep_bf16<<<(total + 255) / 256, 256, 0, stream>>>(W_ih, W_hh, W_pool, Wg, Wpb);
        nnlstm_mfma<<<grid, 256, 0, stream>>>(
            obs1, obs2, h, c, W_emb, b_emb, Wg, b_ih, b_hh, Wpb, b_pool, n, out);
    } else {
        nnlstm_fallback<<<grid, 256, 0, stream>>>(
            obs1, obs2, h, c, W_emb, b_emb, W_ih, b_ih, W_hh, b_hh,
            W_pool, b_pool, n, out);
    }
}